// Round 1
// baseline (1360.126 us; speedup 1.0000x reference)
//
#include <hip/hip_runtime.h>

#define NSEG 2048
#define NCOL 512
#define NC4  128   // float4 per row

// Pass 1: grid-stride over (row, col4) work items. Coalesced float4 loads of x,
// atomicAdd into the per-segment sum (accumulated directly in d_out).
// Counts accumulated once per row (c4 == 0 lane).
__global__ void scatter_sum_kernel(const float4* __restrict__ x,
                                   const int* __restrict__ idx,
                                   float* __restrict__ outsum,
                                   float* __restrict__ cnt,
                                   int nrows) {
    const int total  = nrows * NC4;                 // 25.6M < 2^31
    const int stride = gridDim.x * blockDim.x;
    for (int w = blockIdx.x * blockDim.x + threadIdx.x; w < total; w += stride) {
        const int row = w >> 7;          // / NC4
        const int c4  = w & (NC4 - 1);   // % NC4
        const int seg = idx[row];        // broadcast across 128 consecutive lanes
        const float4 v = x[w];
        float* o = outsum + (size_t)seg * NCOL + (c4 << 2);
        atomicAdd(o + 0, v.x);
        atomicAdd(o + 1, v.y);
        atomicAdd(o + 2, v.z);
        atomicAdd(o + 3, v.w);
        if (c4 == 0) atomicAdd(cnt + seg, 1.0f);
    }
}

// Pass 2: out[s][c] = sum / max(count[s], 1)  (in place, float4-vectorized)
__global__ void finalize_kernel(float4* __restrict__ out,
                                const float* __restrict__ cnt) {
    const int i = blockIdx.x * blockDim.x + threadIdx.x;   // over NSEG*NC4
    if (i < NSEG * NC4) {
        const int s = i >> 7;                              // segment id
        const float inv = 1.0f / fmaxf(cnt[s], 1.0f);
        float4 v = out[i];
        v.x *= inv; v.y *= inv; v.z *= inv; v.w *= inv;
        out[i] = v;
    }
}

extern "C" void kernel_launch(void* const* d_in, const int* in_sizes, int n_in,
                              void* d_out, int out_size, void* d_ws, size_t ws_size,
                              hipStream_t stream) {
    const float* x   = (const float*)d_in[0];
    const int*   idx = (const int*)d_in[1];   // harness passes integer inputs as int32
    float* out = (float*)d_out;               // [NSEG, NCOL] f32
    float* cnt = (float*)d_ws;                // [NSEG] f32 counts in workspace

    const int nrows = in_sizes[1];            // 200000

    // Zero accumulators (harness poisons d_out/d_ws to 0xAA; we must init).
    hipMemsetAsync(d_out, 0, (size_t)NSEG * NCOL * sizeof(float), stream);
    hipMemsetAsync(d_ws,  0, (size_t)NSEG * sizeof(float), stream);

    // Pass 1: sums + counts. ~25.6M float4 items; 2048 blocks x 256 threads,
    // each thread does ~49 grid-stride iterations.
    scatter_sum_kernel<<<2048, 256, 0, stream>>>(
        (const float4*)x, idx, out, cnt, nrows);

    // Pass 2: divide by counts.
    finalize_kernel<<<(NSEG * NC4 + 255) / 256, 256, 0, stream>>>(
        (float4*)out, cnt);
}

// Round 2
// 141.752 us; speedup vs baseline: 9.5951x; 9.5951x over previous
//
#include <hip/hip_runtime.h>

#define NSEG 2048
#define NCOL 512
#define NC2  256   // float2 per row

// Workspace layout (ints):
//   counts  [NSEG]    @ 0
//   offsets [NSEG]    @ NSEG
//   cursor  [NSEG]    @ 2*NSEG
//   rowids  [nrows]   @ 3*NSEG
// Total: 3*2048*4 + 200000*4 = 824,576 bytes.

// K1: histogram of segment ids (int atomics on 2048 counters — cheap).
__global__ void hist_kernel(const int* __restrict__ idx, int* __restrict__ counts, int n) {
    const int stride = gridDim.x * blockDim.x;
    for (int i = blockIdx.x * blockDim.x + threadIdx.x; i < n; i += stride)
        atomicAdd(&counts[idx[i]], 1);
}

// K2: exclusive scan of counts[2048] -> offsets[2048]. Single block, 256 thr x 8.
__global__ void scan_kernel(const int* __restrict__ counts, int* __restrict__ offsets) {
    __shared__ int lds[256];
    const int t = threadIdx.x;
    int local[8];
    int s = 0;
    #pragma unroll
    for (int j = 0; j < 8; ++j) {          // exclusive prefix within chunk
        local[j] = s;
        s += counts[t * 8 + j];
    }
    lds[t] = s;
    __syncthreads();
    // Hillis-Steele inclusive scan over 256 thread-sums
    for (int off = 1; off < 256; off <<= 1) {
        int add = (t >= off) ? lds[t - off] : 0;
        __syncthreads();
        lds[t] += add;
        __syncthreads();
    }
    const int base = lds[t] - s;           // exclusive
    #pragma unroll
    for (int j = 0; j < 8; ++j)
        offsets[t * 8 + j] = base + local[j];
}

// K3: scatter row ids into per-segment contiguous lists.
__global__ void build_rows_kernel(const int* __restrict__ idx,
                                  const int* __restrict__ offsets,
                                  int* __restrict__ cursor,
                                  int* __restrict__ rowids, int n) {
    const int stride = gridDim.x * blockDim.x;
    for (int i = blockIdx.x * blockDim.x + threadIdx.x; i < n; i += stride) {
        const int s = idx[i];
        const int p = atomicAdd(&cursor[s], 1);
        rowids[offsets[s] + p] = i;
    }
}

// K4: gather-sum. Block b = segment b. 256 threads x float2 = one 512-col row
// per inner iteration (2 KB contiguous, fully coalesced). Row-ids staged in LDS.
__global__ void gather_mean_kernel(const float2* __restrict__ x,
                                   const int* __restrict__ rowids,
                                   const int* __restrict__ offsets,
                                   const int* __restrict__ counts,
                                   float2* __restrict__ out) {
    __shared__ int rlds[256];
    const int s = blockIdx.x;
    const int start = offsets[s];
    const int cnt   = counts[s];
    const int t     = threadIdx.x;

    float2 acc = make_float2(0.f, 0.f);
    for (int base = 0; base < cnt; base += 256) {
        const int m = min(256, cnt - base);
        __syncthreads();
        if (t < m) rlds[t] = rowids[start + base + t];
        __syncthreads();
        #pragma unroll 4
        for (int i = 0; i < m; ++i) {
            const int r = rlds[i];                       // LDS broadcast (free)
            const float2 v = x[(size_t)r * NC2 + t];
            acc.x += v.x;
            acc.y += v.y;
        }
    }
    const float inv = 1.0f / fmaxf((float)cnt, 1.0f);
    out[(size_t)s * NC2 + t] = make_float2(acc.x * inv, acc.y * inv);
}

extern "C" void kernel_launch(void* const* d_in, const int* in_sizes, int n_in,
                              void* d_out, int out_size, void* d_ws, size_t ws_size,
                              hipStream_t stream) {
    const float* x   = (const float*)d_in[0];
    const int*   idx = (const int*)d_in[1];
    float* out = (float*)d_out;
    const int nrows = in_sizes[1];            // 200000

    int* counts  = (int*)d_ws;
    int* offsets = counts + NSEG;
    int* cursor  = offsets + NSEG;
    int* rowids  = cursor + NSEG;

    // Zero counts/offsets/cursor (rowids fully overwritten by K3).
    hipMemsetAsync(d_ws, 0, (size_t)3 * NSEG * sizeof(int), stream);

    hist_kernel<<<256, 256, 0, stream>>>(idx, counts, nrows);
    scan_kernel<<<1, 256, 0, stream>>>(counts, offsets);
    build_rows_kernel<<<256, 256, 0, stream>>>(idx, offsets, cursor, rowids, nrows);
    gather_mean_kernel<<<NSEG, 256, 0, stream>>>(
        (const float2*)x, rowids, offsets, counts, (float2*)out);
}

// Round 3
// 140.200 us; speedup vs baseline: 9.7013x; 1.0111x over previous
//
#include <hip/hip_runtime.h>

#define NSEG 2048
#define NCOL 512
#define NC4  128   // float4 per row

// Workspace layout (ints):
//   counts  [NSEG]    @ 0
//   offsets [NSEG]    @ NSEG
//   cursor  [NSEG]    @ 2*NSEG
//   rowids  [nrows]   @ 3*NSEG

// K1: histogram of segment ids (int atomics on 2048 counters — cheap).
__global__ void hist_kernel(const int* __restrict__ idx, int* __restrict__ counts, int n) {
    const int stride = gridDim.x * blockDim.x;
    for (int i = blockIdx.x * blockDim.x + threadIdx.x; i < n; i += stride)
        atomicAdd(&counts[idx[i]], 1);
}

// K2: exclusive scan of counts[2048] -> offsets[2048]. Single block, 256 thr x 8.
__global__ void scan_kernel(const int* __restrict__ counts, int* __restrict__ offsets) {
    __shared__ int lds[256];
    const int t = threadIdx.x;
    int local[8];
    int s = 0;
    #pragma unroll
    for (int j = 0; j < 8; ++j) {          // exclusive prefix within chunk
        local[j] = s;
        s += counts[t * 8 + j];
    }
    lds[t] = s;
    __syncthreads();
    for (int off = 1; off < 256; off <<= 1) {
        int add = (t >= off) ? lds[t - off] : 0;
        __syncthreads();
        lds[t] += add;
        __syncthreads();
    }
    const int base = lds[t] - s;           // exclusive
    #pragma unroll
    for (int j = 0; j < 8; ++j)
        offsets[t * 8 + j] = base + local[j];
}

// K3: scatter row ids into per-segment contiguous lists.
__global__ void build_rows_kernel(const int* __restrict__ idx,
                                  const int* __restrict__ offsets,
                                  int* __restrict__ cursor,
                                  int* __restrict__ rowids, int n) {
    const int stride = gridDim.x * blockDim.x;
    for (int i = blockIdx.x * blockDim.x + threadIdx.x; i < n; i += stride) {
        const int s = idx[i];
        const int p = atomicAdd(&cursor[s], 1);
        rowids[offsets[s] + p] = i;
    }
}

// K4: gather-sum. Block b = segment b. 256 threads process TWO rows per
// iteration: half = t>>7 selects even/odd row, c4 = t&127 selects the float4
// column. 16 B/lane coalesced loads (1 KiB per wave-instruction), 2 rows in
// flight. Cross-half reduction via LDS at the end; division fused.
__global__ void gather_mean_kernel(const float4* __restrict__ x,
                                   const int* __restrict__ rowids,
                                   const int* __restrict__ offsets,
                                   const int* __restrict__ counts,
                                   float4* __restrict__ out) {
    __shared__ int rlds[256];
    __shared__ float4 partial[NC4];
    const int s = blockIdx.x;
    const int start = offsets[s];
    const int cnt   = counts[s];
    const int t     = threadIdx.x;
    const int half  = t >> 7;        // 0 or 1
    const int c4    = t & (NC4 - 1);

    float4 acc = make_float4(0.f, 0.f, 0.f, 0.f);
    for (int base = 0; base < cnt; base += 256) {
        const int m = min(256, cnt - base);
        __syncthreads();
        if (t < m) rlds[t] = rowids[start + base + t];
        __syncthreads();
        #pragma unroll 4
        for (int i = half; i < m; i += 2) {
            const int r = rlds[i];                       // LDS broadcast
            const float4 v = x[(size_t)r * NC4 + c4];
            acc.x += v.x; acc.y += v.y; acc.z += v.z; acc.w += v.w;
        }
    }
    if (half) partial[c4] = acc;
    __syncthreads();
    if (!half) {
        const float4 p = partial[c4];
        const float inv = 1.0f / fmaxf((float)cnt, 1.0f);
        float4 o;
        o.x = (acc.x + p.x) * inv;
        o.y = (acc.y + p.y) * inv;
        o.z = (acc.z + p.z) * inv;
        o.w = (acc.w + p.w) * inv;
        out[(size_t)s * NC4 + c4] = o;
    }
}

extern "C" void kernel_launch(void* const* d_in, const int* in_sizes, int n_in,
                              void* d_out, int out_size, void* d_ws, size_t ws_size,
                              hipStream_t stream) {
    const float* x   = (const float*)d_in[0];
    const int*   idx = (const int*)d_in[1];
    float* out = (float*)d_out;
    const int nrows = in_sizes[1];            // 200000

    int* counts  = (int*)d_ws;
    int* offsets = counts + NSEG;
    int* cursor  = offsets + NSEG;
    int* rowids  = cursor + NSEG;

    hipMemsetAsync(d_ws, 0, (size_t)3 * NSEG * sizeof(int), stream);

    hist_kernel<<<256, 256, 0, stream>>>(idx, counts, nrows);
    scan_kernel<<<1, 256, 0, stream>>>(counts, offsets);
    build_rows_kernel<<<256, 256, 0, stream>>>(idx, offsets, cursor, rowids, nrows);
    gather_mean_kernel<<<NSEG, 256, 0, stream>>>(
        (const float4*)x, rowids, offsets, counts, (float4*)out);
}